// Round 3
// baseline (292.044 us; speedup 1.0000x reference)
//
#include <hip/hip_runtime.h>
#include <math.h>

// QuantumIntegrator: r_embed [B=4, S=4096, 2] fp32, dt [4] fp32.
// Outputs (flat fp32): r_final [4,4096,2] then score [4,4096,4096].
//
// R6 theory: wave-per-row rewrite (R4) was NEUTRAL vs block-per-row -> the
// reduce structure was never the cost. Invariant cost = score-store phase
// coupled in-wave behind the triangular reduce + shfl chain (and NT stores
// regressed ~13us vs plain: R0 273.9 -> R2 287.1). Fix: decouple.
//   k_reduce1: wave-per-row triangular reduce on r -> r_mid,k1,sum,inv (~5us)
//   k_score:   PURE streaming score writer, loads precomputed inv, plain
//              dwordx4 stores (fill proves plain stores reach 6.3+ TB/s) (~45us)
//   k_pass2:   wave-per-row reduce on r_mid -> r_final (~5-10us)
// Prediction: kernel sum ~116 -> ~65us. dur_us 287 -> ~235 if the ~170us
// re-poison fill is inside the timed graph; -> ~70 if not. If dur stays
// ~285, the store path itself is the floor -> attack store pattern next.

#define S_LEN 4096
#define ROWS  16384   // B*S with B=4 (fixed by setup_inputs)
#define BLK   256     // 4 independent waves per block
#define EPSF  1e-6f
#define RATE  0.01f
#define MINR  0.1f
#define MAXR  2.0f

// ws layout (floats):
//   [0,      2*ROWS) r_mid
//   [2*ROWS, 4*ROWS) k1
//   [4*ROWS, 5*ROWS) sum_score (D/dc)
//   [5*ROWS, 6*ROWS) inv (1/dc)

__global__ __launch_bounds__(BLK) void k_reduce1(
    const float2* __restrict__ r_in,
    const float*  __restrict__ dt_in,
    float* __restrict__ ws)
{
    const int lane = threadIdx.x & 63;
    const int row  = (blockIdx.x << 2) + (threadIdx.x >> 6);   // wave-per-row
    const int b = row >> 12;
    const int s = row & (S_LEN - 1);
    const float2* rb  = r_in + ((size_t)b << 12);
    const float4* rb4 = (const float4*)rb;        // one float4 = points (2i, 2i+1)
    const float2 rs = rb[s];

    // Triangular reduce: denom + context numerator. Coalesced float4, L1-hot.
    float dsum = 0.f, nx = 0.f, ny = 0.f;
    for (int i = lane; 2*i <= s; i += 64) {
        float4 p = rb4[i];
        float d0 = fmaxf(rs.x * p.x + rs.y * p.y, 0.f);
        dsum += d0; nx = fmaf(d0, p.x, nx); ny = fmaf(d0, p.y, ny);
        if (2*i + 1 <= s) {
            float d1 = fmaxf(rs.x * p.z + rs.y * p.w, 0.f);
            dsum += d1; nx = fmaf(d1, p.z, nx); ny = fmaf(d1, p.w, ny);
        }
    }
    #pragma unroll
    for (int off = 32; off > 0; off >>= 1) {
        dsum += __shfl_down(dsum, off);
        nx   += __shfl_down(nx, off);
        ny   += __shfl_down(ny, off);
    }

    if (lane == 0) {
        const float D   = dsum;
        const float dc  = fmaxf(D, EPSF);
        const float dtb = dt_in[b];
        float k1x = dtb * nx / dc;
        float k1y = dtb * ny / dc;
        if (!isfinite(k1x)) k1x = 0.f;
        if (!isfinite(k1y)) k1y = 0.f;
        float rmx = rs.x + k1x, rmy = rs.y + k1y;
        if (!isfinite(rmx)) rmx = rs.x;
        if (!isfinite(rmy)) rmy = rs.y;
        ws[2*row]              = rmx;  ws[2*row + 1]          = rmy;  // r_mid
        ws[2*ROWS + 2*row]     = k1x;  ws[2*ROWS + 2*row + 1] = k1y;  // k1
        ws[4*ROWS + row]       = D / dc;       // row-sum of normalized score
        ws[5*ROWS + row]       = 1.f / dc;     // inv for the score writer
    }
}

// Pure streaming score writer. No reduce, no shfl, nothing ahead of the
// store stream but two 8B/4B scalar loads. Plain stores (not NT).
__global__ __launch_bounds__(BLK) void k_score(
    const float2* __restrict__ r_in,
    const float*  __restrict__ ws,
    float* __restrict__ score_out)                // fp32, [ROWS, S_LEN]
{
    const int lane = threadIdx.x & 63;
    const int row  = (blockIdx.x << 2) + (threadIdx.x >> 6);
    const int b = row >> 12;
    const int s = row & (S_LEN - 1);
    const float2* rb  = r_in + ((size_t)b << 12);
    const float4* rb4 = (const float4*)rb;
    const float2 rs = rb[s];
    const float inv = ws[5*ROWS + row];

    // relu(dot)*inv == relu(dot*inv) since inv > 0.
    const float isx = rs.x * inv, isy = rs.y * inv;
    float* orow = score_out + (size_t)row * S_LEN;
    #pragma unroll 4
    for (int q = 0; q < 16; q++) {
        const int t0 = (lane << 2) + (q << 8);    // 4*lane + 256*q
        float4 v = make_float4(0.f, 0.f, 0.f, 0.f);
        if ((q << 8) <= s) {                      // wave-uniform skip of zero tail
            if (t0 <= s) {
                const float4 p01 = rb4[t0 >> 1];        // points t0, t0+1
                const float4 p23 = rb4[(t0 >> 1) + 1];  // points t0+2, t0+3 (t0+3 <= 4095)
                v.x = fmaxf(isx * p01.x + isy * p01.y, 0.f);
                v.y = (t0 + 1 <= s) ? fmaxf(isx * p01.z + isy * p01.w, 0.f) : 0.f;
                v.z = (t0 + 2 <= s) ? fmaxf(isx * p23.x + isy * p23.y, 0.f) : 0.f;
                v.w = (t0 + 3 <= s) ? fmaxf(isx * p23.z + isy * p23.w, 0.f) : 0.f;
            }
        }
        *((float4*)(orow + t0)) = v;
    }
}

__global__ __launch_bounds__(BLK) void k_pass2(
    const float2* __restrict__ r_in,
    const float*  __restrict__ dt_in,
    const float*  __restrict__ ws,
    float* __restrict__ rfinal_out)               // fp32, [ROWS, 2]
{
    const int lane = threadIdx.x & 63;
    const int row  = (blockIdx.x << 2) + (threadIdx.x >> 6);
    const int b = row >> 12;
    const int s = row & (S_LEN - 1);
    const float2* rm  = ((const float2*)ws) + ((size_t)b << 12);   // r_mid for batch
    const float4* rm4 = (const float4*)rm;
    const float2 rs = rm[s];

    float dsum = 0.f, nx = 0.f, ny = 0.f;
    for (int i = lane; 2*i <= s; i += 64) {
        float4 p = rm4[i];
        float d0 = fmaxf(rs.x * p.x + rs.y * p.y, 0.f);
        dsum += d0; nx = fmaf(d0, p.x, nx); ny = fmaf(d0, p.y, ny);
        if (2*i + 1 <= s) {
            float d1 = fmaxf(rs.x * p.z + rs.y * p.w, 0.f);
            dsum += d1; nx = fmaf(d1, p.z, nx); ny = fmaf(d1, p.w, ny);
        }
    }
    #pragma unroll
    for (int off = 32; off > 0; off >>= 1) {
        dsum += __shfl_down(dsum, off);
        nx   += __shfl_down(nx, off);
        ny   += __shfl_down(ny, off);
    }

    if (lane == 0) {
        const float dc  = fmaxf(dsum, EPSF);
        const float dtb = dt_in[b];
        float k2x = dtb * nx / dc;
        float k2y = dtb * ny / dc;
        if (!isfinite(k2x)) k2x = 0.f;
        if (!isfinite(k2y)) k2y = 0.f;
        const float2 r0  = r_in[row];
        const float  k1x = ws[2*ROWS + 2*row], k1y = ws[2*ROWS + 2*row + 1];
        const float rnx = r0.x + 0.5f * (k1x + k2x);
        const float rny = r0.y + 0.5f * (k1y + k2y);
        const float nr  = fmaxf(sqrtf(rnx*rnx + rny*rny), EPSF);
        const float ar  = fminf(fmaxf(nr + ws[4*ROWS + row] * RATE, MINR), MAXR);
        const float sc  = ar / nr;
        float fx = rnx * sc, fy = rny * sc;
        if (!isfinite(fx)) fx = r0.x;
        if (!isfinite(fy)) fy = r0.y;
        rfinal_out[2*row]     = fx;
        rfinal_out[2*row + 1] = fy;
    }
}

extern "C" void kernel_launch(void* const* d_in, const int* in_sizes, int n_in,
                              void* d_out, int out_size, void* d_ws, size_t ws_size,
                              hipStream_t stream) {
    const float2* r_in  = (const float2*)d_in[0];   // fp32 [4,4096,2]
    const float*  dt_in = (const float*)d_in[1];    // fp32 [4]
    float* out = (float*)d_out;
    float* ws  = (float*)d_ws;

    // d_out: first ROWS*2 floats = r_final, then ROWS*S_LEN floats = score.
    float* rfinal_out = out;
    float* score_out  = out + (size_t)2 * ROWS;

    hipLaunchKernelGGL(k_reduce1, dim3(ROWS / 4), dim3(BLK), 0, stream,
                       r_in, dt_in, ws);
    hipLaunchKernelGGL(k_score,   dim3(ROWS / 4), dim3(BLK), 0, stream,
                       r_in, ws, score_out);
    hipLaunchKernelGGL(k_pass2,   dim3(ROWS / 4), dim3(BLK), 0, stream,
                       r_in, dt_in, ws, rfinal_out);
}

// Round 4
// 283.361 us; speedup vs baseline: 1.0306x; 1.0306x over previous
//
#include <hip/hip_runtime.h>
#include <math.h>

// QuantumIntegrator: r_embed [B=4, S=4096, 2] fp32, dt [4] fp32.
// Outputs (flat fp32): r_final [4,4096,2] then score [4,4096,4096].
//
// R7 model (from R0/R2/R3 invariance): timed graph = poison fill (1.074 GB
// = exactly 4*out_size, ~168us @ 6.5 TB/s, harness-fixed) + our kernels
// (~105-125us). Score-write floor = 268 MB / 6.4 TB/s ~= 42us. Remaining
// controllable cost = reduce kernels (~20us) + per-node gaps/serialization
// (R3's 3 kernels was worst, R0's 2 kernels best). This version: minimum
// node count (2 kernels), wave-per-row reduces (no LDS/barriers), score
// stores issue first in K2 (fire-and-forget) with pass-2's triangular
// reduce + finalize hidden under the store drain. Plain dwordx4 stores
// (NT measured neutral-to-worse in R2).
// Conservation floor: (1.074+0.268) GB @ 6.4 TB/s ~= 209us + ~40us
// irreducible => ~250us. Prediction: 260-275us. If >=285, we are at the
// harness roofline (4 structural variants invariant).

#define S_LEN 4096
#define ROWS  16384   // B*S with B=4 (fixed by setup_inputs)
#define BLK   256     // 4 independent waves per block
#define EPSF  1e-6f
#define RATE  0.01f
#define MINR  0.1f
#define MAXR  2.0f

// ws layout (floats):
//   [0,      2*ROWS) r_mid
//   [2*ROWS, 4*ROWS) k1
//   [4*ROWS, 5*ROWS) sum_score (D/dc)
//   [5*ROWS, 6*ROWS) inv (1/dc)

__global__ __launch_bounds__(BLK) void k_prep(
    const float2* __restrict__ r_in,
    const float*  __restrict__ dt_in,
    float* __restrict__ ws)
{
    const int lane = threadIdx.x & 63;
    const int row  = (blockIdx.x << 2) + (threadIdx.x >> 6);   // wave-per-row
    const int b = row >> 12;
    const int s = row & (S_LEN - 1);
    const float2* rb  = r_in + ((size_t)b << 12);
    const float4* rb4 = (const float4*)rb;        // one float4 = points (2i, 2i+1)
    const float2 rs = rb[s];

    // Triangular reduce: denom + context numerator. Coalesced float4, L1-hot.
    float dsum = 0.f, nx = 0.f, ny = 0.f;
    for (int i = lane; 2*i <= s; i += 64) {
        float4 p = rb4[i];
        float d0 = fmaxf(rs.x * p.x + rs.y * p.y, 0.f);
        dsum += d0; nx = fmaf(d0, p.x, nx); ny = fmaf(d0, p.y, ny);
        if (2*i + 1 <= s) {
            float d1 = fmaxf(rs.x * p.z + rs.y * p.w, 0.f);
            dsum += d1; nx = fmaf(d1, p.z, nx); ny = fmaf(d1, p.w, ny);
        }
    }
    #pragma unroll
    for (int off = 32; off > 0; off >>= 1) {
        dsum += __shfl_down(dsum, off);
        nx   += __shfl_down(nx, off);
        ny   += __shfl_down(ny, off);
    }

    if (lane == 0) {
        const float D   = dsum;
        const float dc  = fmaxf(D, EPSF);
        const float dtb = dt_in[b];
        float k1x = dtb * nx / dc;
        float k1y = dtb * ny / dc;
        if (!isfinite(k1x)) k1x = 0.f;
        if (!isfinite(k1y)) k1y = 0.f;
        float rmx = rs.x + k1x, rmy = rs.y + k1y;
        if (!isfinite(rmx)) rmx = rs.x;
        if (!isfinite(rmy)) rmy = rs.y;
        ws[2*row]              = rmx;  ws[2*row + 1]          = rmy;  // r_mid
        ws[2*ROWS + 2*row]     = k1x;  ws[2*ROWS + 2*row + 1] = k1y;  // k1
        ws[4*ROWS + row]       = D / dc;       // row-sum of normalized score
        ws[5*ROWS + row]       = 1.f / dc;     // inv for the score writer
    }
}

// K2: score stream first (fire-and-forget stores, only a 1-dword inv load
// ahead of them), then pass-2 triangular reduce on r_mid (L2-hot) + r_final
// finalize, hidden under the store drain.
__global__ __launch_bounds__(BLK) void k_main(
    const float2* __restrict__ r_in,
    const float*  __restrict__ dt_in,
    const float*  __restrict__ ws,
    float* __restrict__ score_out,                // fp32, [ROWS, S_LEN]
    float* __restrict__ rfinal_out)               // fp32, [ROWS, 2]
{
    const int lane = threadIdx.x & 63;
    const int row  = (blockIdx.x << 2) + (threadIdx.x >> 6);
    const int b = row >> 12;
    const int s = row & (S_LEN - 1);
    const float2* rb  = r_in + ((size_t)b << 12);
    const float4* rb4 = (const float4*)rb;
    const float2 rs = rb[s];
    const float inv = ws[5*ROWS + row];

    // ---- Phase 1: stream the 16 KB score row. relu(dot)*inv == relu(dot*inv).
    const float isx = rs.x * inv, isy = rs.y * inv;
    float* orow = score_out + (size_t)row * S_LEN;
    #pragma unroll 4
    for (int q = 0; q < 16; q++) {
        const int t0 = (lane << 2) + (q << 8);    // 4*lane + 256*q
        float4 v = make_float4(0.f, 0.f, 0.f, 0.f);
        if ((q << 8) <= s) {                      // wave-uniform skip of zero tail
            if (t0 <= s) {
                const float4 p01 = rb4[t0 >> 1];        // points t0, t0+1
                const float4 p23 = rb4[(t0 >> 1) + 1];  // points t0+2, t0+3 (t0+3 <= 4095)
                v.x = fmaxf(isx * p01.x + isy * p01.y, 0.f);
                v.y = (t0 + 1 <= s) ? fmaxf(isx * p01.z + isy * p01.w, 0.f) : 0.f;
                v.z = (t0 + 2 <= s) ? fmaxf(isx * p23.x + isy * p23.y, 0.f) : 0.f;
                v.w = (t0 + 3 <= s) ? fmaxf(isx * p23.z + isy * p23.w, 0.f) : 0.f;
            }
        }
        *((float4*)(orow + t0)) = v;
    }

    // ---- Phase 2: pass-2 triangular reduce on r_mid (ws, L2-hot).
    const float2* rm  = (const float2*)ws + ((size_t)b << 12);
    const float4* rm4 = (const float4*)rm;
    const float2 ms = rm[s];

    float dsum = 0.f, nx = 0.f, ny = 0.f;
    for (int i = lane; 2*i <= s; i += 64) {
        float4 p = rm4[i];
        float d0 = fmaxf(ms.x * p.x + ms.y * p.y, 0.f);
        dsum += d0; nx = fmaf(d0, p.x, nx); ny = fmaf(d0, p.y, ny);
        if (2*i + 1 <= s) {
            float d1 = fmaxf(ms.x * p.z + ms.y * p.w, 0.f);
            dsum += d1; nx = fmaf(d1, p.z, nx); ny = fmaf(d1, p.w, ny);
        }
    }
    #pragma unroll
    for (int off = 32; off > 0; off >>= 1) {
        dsum += __shfl_down(dsum, off);
        nx   += __shfl_down(nx, off);
        ny   += __shfl_down(ny, off);
    }

    if (lane == 0) {
        const float dc  = fmaxf(dsum, EPSF);
        const float dtb = dt_in[b];
        float k2x = dtb * nx / dc;
        float k2y = dtb * ny / dc;
        if (!isfinite(k2x)) k2x = 0.f;
        if (!isfinite(k2y)) k2y = 0.f;
        const float2 r0  = r_in[row];
        const float  k1x = ws[2*ROWS + 2*row], k1y = ws[2*ROWS + 2*row + 1];
        const float rnx = r0.x + 0.5f * (k1x + k2x);
        const float rny = r0.y + 0.5f * (k1y + k2y);
        const float nr  = fmaxf(sqrtf(rnx*rnx + rny*rny), EPSF);
        const float ar  = fminf(fmaxf(nr + ws[4*ROWS + row] * RATE, MINR), MAXR);
        const float sc  = ar / nr;
        float fx = rnx * sc, fy = rny * sc;
        if (!isfinite(fx)) fx = r0.x;
        if (!isfinite(fy)) fy = r0.y;
        rfinal_out[2*row]     = fx;
        rfinal_out[2*row + 1] = fy;
    }
}

extern "C" void kernel_launch(void* const* d_in, const int* in_sizes, int n_in,
                              void* d_out, int out_size, void* d_ws, size_t ws_size,
                              hipStream_t stream) {
    const float2* r_in  = (const float2*)d_in[0];   // fp32 [4,4096,2]
    const float*  dt_in = (const float*)d_in[1];    // fp32 [4]
    float* out = (float*)d_out;
    float* ws  = (float*)d_ws;

    // d_out: first ROWS*2 floats = r_final, then ROWS*S_LEN floats = score.
    float* rfinal_out = out;
    float* score_out  = out + (size_t)2 * ROWS;

    hipLaunchKernelGGL(k_prep, dim3(ROWS / 4), dim3(BLK), 0, stream,
                       r_in, dt_in, ws);
    hipLaunchKernelGGL(k_main, dim3(ROWS / 4), dim3(BLK), 0, stream,
                       r_in, dt_in, ws, score_out, rfinal_out);
}

// Round 5
// 276.233 us; speedup vs baseline: 1.0572x; 1.0258x over previous
//
#include <hip/hip_runtime.h>
#include <math.h>

// QuantumIntegrator: r_embed [B=4, S=4096, 2] fp32, dt [4] fp32.
// Outputs (flat fp32): r_final [4,4096,2] then score [4,4096,4096].
//
// R8 theory: all four prior variants (274-292us) interleave global operand
// loads with the score stores. vmcnt is IN-ORDER: every load-use wait also
// drains all earlier stores in the wave's queue -> store stream throttled
// to ~2.7 TB/s while the loads-free harness fill hits 6.6 TB/s on the same
// memory. Fix: stage the batch's r-row (32 KB) in LDS once per block; the
// store loop then has ONLY stores in the vmcnt queue (operands via ds_read,
// lgkmcnt) -> fire-and-forget stores at write BW.
// Budget: dur ~= fill(162) + k_prep(5) + k_main + gaps(10). k_main was
// ~100us (2.7 TB/s); floor 41us. Prediction: dur 283 -> ~230 +- 10.
// If invariant again: harness roofline (fill+score = 209us mandatory HBM
// write + ~40us reduces/gaps), declare next round.

#define S_LEN 4096
#define ROWS  16384   // B*S with B=4 (fixed by setup_inputs)
#define BLK   256     // 4 waves per block, 4 consecutive rows (same batch)
#define EPSF  1e-6f
#define RATE  0.01f
#define MINR  0.1f
#define MAXR  2.0f

// ws layout (floats):
//   [0,      2*ROWS) r_mid
//   [2*ROWS, 4*ROWS) k1
//   [4*ROWS, 5*ROWS) sum_score (D/dc)
//   [5*ROWS, 6*ROWS) inv (1/dc)

__global__ __launch_bounds__(BLK) void k_prep(
    const float2* __restrict__ r_in,
    const float*  __restrict__ dt_in,
    float* __restrict__ ws)
{
    const int lane = threadIdx.x & 63;
    const int row  = (blockIdx.x << 2) + (threadIdx.x >> 6);   // wave-per-row
    const int b = row >> 12;
    const int s = row & (S_LEN - 1);
    const float2* rb  = r_in + ((size_t)b << 12);
    const float4* rb4 = (const float4*)rb;        // one float4 = points (2i, 2i+1)
    const float2 rs = rb[s];

    // Triangular reduce: denom + context numerator. Coalesced float4, L1-hot.
    float dsum = 0.f, nx = 0.f, ny = 0.f;
    for (int i = lane; 2*i <= s; i += 64) {
        float4 p = rb4[i];
        float d0 = fmaxf(rs.x * p.x + rs.y * p.y, 0.f);
        dsum += d0; nx = fmaf(d0, p.x, nx); ny = fmaf(d0, p.y, ny);
        if (2*i + 1 <= s) {
            float d1 = fmaxf(rs.x * p.z + rs.y * p.w, 0.f);
            dsum += d1; nx = fmaf(d1, p.z, nx); ny = fmaf(d1, p.w, ny);
        }
    }
    #pragma unroll
    for (int off = 32; off > 0; off >>= 1) {
        dsum += __shfl_down(dsum, off);
        nx   += __shfl_down(nx, off);
        ny   += __shfl_down(ny, off);
    }

    if (lane == 0) {
        const float D   = dsum;
        const float dc  = fmaxf(D, EPSF);
        const float dtb = dt_in[b];
        float k1x = dtb * nx / dc;
        float k1y = dtb * ny / dc;
        if (!isfinite(k1x)) k1x = 0.f;
        if (!isfinite(k1y)) k1y = 0.f;
        float rmx = rs.x + k1x, rmy = rs.y + k1y;
        if (!isfinite(rmx)) rmx = rs.x;
        if (!isfinite(rmy)) rmy = rs.y;
        ws[2*row]              = rmx;  ws[2*row + 1]          = rmy;  // r_mid
        ws[2*ROWS + 2*row]     = k1x;  ws[2*ROWS + 2*row + 1] = k1y;  // k1
        ws[4*ROWS + row]       = D / dc;       // row-sum of normalized score
        ws[5*ROWS + row]       = 1.f / dc;     // inv for the score writer
    }
}

// K2: LDS-staged score stream (vmcnt queue = stores ONLY), then pass-2
// triangular reduce on r_mid (global, L2-hot) + r_final finalize.
__global__ __launch_bounds__(BLK) void k_main(
    const float2* __restrict__ r_in,
    const float*  __restrict__ dt_in,
    const float*  __restrict__ ws,
    float* __restrict__ score_out,                // fp32, [ROWS, S_LEN]
    float* __restrict__ rfinal_out)               // fp32, [ROWS, 2]
{
    __shared__ float4 lds4[2048];                 // 32 KB: batch r as pairs (2i,2i+1)

    const int lane = threadIdx.x & 63;
    const int row  = (blockIdx.x << 2) + (threadIdx.x >> 6);
    const int b = row >> 12;                      // uniform across the block
    const int s = row & (S_LEN - 1);
    const float4* rb4 = (const float4*)(r_in + ((size_t)b << 12));

    // Stage the batch's whole r row-set into LDS (shared by all 4 waves).
    #pragma unroll
    for (int k = 0; k < 8; k++)
        lds4[threadIdx.x + (k << 8)] = rb4[threadIdx.x + (k << 8)];

    const float2 rs  = ((const float2*)r_in)[((size_t)b << 12) + s];
    const float  inv = ws[5*ROWS + row];
    __syncthreads();

    // ---- Phase 1: stream the 16 KB score row. Operands from LDS (lgkmcnt),
    // stores are the only vmcnt ops -> never waited on inside the loop.
    const float isx = rs.x * inv, isy = rs.y * inv;   // relu(dot)*inv == relu(dot*inv)
    float* orow = score_out + (size_t)row * S_LEN;
    #pragma unroll 4
    for (int q = 0; q < 16; q++) {
        const int t0 = (lane << 2) + (q << 8);    // 4*lane + 256*q
        float4 v = make_float4(0.f, 0.f, 0.f, 0.f);
        if ((q << 8) <= s) {                      // wave-uniform skip of zero tail
            if (t0 <= s) {
                const float4 p01 = lds4[t0 >> 1];        // points t0, t0+1
                const float4 p23 = lds4[(t0 >> 1) + 1];  // points t0+2, t0+3
                v.x = fmaxf(isx * p01.x + isy * p01.y, 0.f);
                v.y = (t0 + 1 <= s) ? fmaxf(isx * p01.z + isy * p01.w, 0.f) : 0.f;
                v.z = (t0 + 2 <= s) ? fmaxf(isx * p23.x + isy * p23.y, 0.f) : 0.f;
                v.w = (t0 + 3 <= s) ? fmaxf(isx * p23.z + isy * p23.w, 0.f) : 0.f;
            }
        }
        *((float4*)(orow + t0)) = v;
    }

    // ---- Phase 2: pass-2 triangular reduce on r_mid (ws, L2-hot). Its first
    // load-wait drains this wave's stores once; other waves cover the pipe.
    const float4* rm4 = (const float4*)((const float2*)ws + ((size_t)b << 12));
    const float2  ms  = ((const float2*)ws)[((size_t)b << 12) + s];

    float dsum = 0.f, nx = 0.f, ny = 0.f;
    for (int i = lane; 2*i <= s; i += 64) {
        float4 p = rm4[i];
        float d0 = fmaxf(ms.x * p.x + ms.y * p.y, 0.f);
        dsum += d0; nx = fmaf(d0, p.x, nx); ny = fmaf(d0, p.y, ny);
        if (2*i + 1 <= s) {
            float d1 = fmaxf(ms.x * p.z + ms.y * p.w, 0.f);
            dsum += d1; nx = fmaf(d1, p.z, nx); ny = fmaf(d1, p.w, ny);
        }
    }
    #pragma unroll
    for (int off = 32; off > 0; off >>= 1) {
        dsum += __shfl_down(dsum, off);
        nx   += __shfl_down(nx, off);
        ny   += __shfl_down(ny, off);
    }

    if (lane == 0) {
        const float dc  = fmaxf(dsum, EPSF);
        const float dtb = dt_in[b];
        float k2x = dtb * nx / dc;
        float k2y = dtb * ny / dc;
        if (!isfinite(k2x)) k2x = 0.f;
        if (!isfinite(k2y)) k2y = 0.f;
        const float2 r0  = r_in[row];
        const float  k1x = ws[2*ROWS + 2*row], k1y = ws[2*ROWS + 2*row + 1];
        const float rnx = r0.x + 0.5f * (k1x + k2x);
        const float rny = r0.y + 0.5f * (k1y + k2y);
        const float nr  = fmaxf(sqrtf(rnx*rnx + rny*rny), EPSF);
        const float ar  = fminf(fmaxf(nr + ws[4*ROWS + row] * RATE, MINR), MAXR);
        const float sc  = ar / nr;
        float fx = rnx * sc, fy = rny * sc;
        if (!isfinite(fx)) fx = r0.x;
        if (!isfinite(fy)) fy = r0.y;
        rfinal_out[2*row]     = fx;
        rfinal_out[2*row + 1] = fy;
    }
}

extern "C" void kernel_launch(void* const* d_in, const int* in_sizes, int n_in,
                              void* d_out, int out_size, void* d_ws, size_t ws_size,
                              hipStream_t stream) {
    const float2* r_in  = (const float2*)d_in[0];   // fp32 [4,4096,2]
    const float*  dt_in = (const float*)d_in[1];    // fp32 [4]
    float* out = (float*)d_out;
    float* ws  = (float*)d_ws;

    // d_out: first ROWS*2 floats = r_final, then ROWS*S_LEN floats = score.
    float* rfinal_out = out;
    float* score_out  = out + (size_t)2 * ROWS;

    hipLaunchKernelGGL(k_prep, dim3(ROWS / 4), dim3(BLK), 0, stream,
                       r_in, dt_in, ws);
    hipLaunchKernelGGL(k_main, dim3(ROWS / 4), dim3(BLK), 0, stream,
                       r_in, dt_in, ws, score_out, rfinal_out);
}